// Round 3
// baseline (1136.124 us; speedup 1.0000x reference)
//
#include <hip/hip_runtime.h>

// ---------------------------------------------------------------------------
// BiNet R3: balanced edge-parallel gather with segmented wave reduction.
//   * CSR fill sorts edges by slot(dst) (branch-major) -> branch wave-uniform,
//     same-dst edges adjacent.
//   * 1 lane = 1 edge: full 68->32->32 MLP in registers, weights scalar.
//   * segmented shfl-up scan over the 32-ch message, atomicAdd only at
//     run ends (~9 per wave instead of 64).
//   * pool_dst staged in out[0:half] (scratch), overwritten by final copy.
// ---------------------------------------------------------------------------

#define IN_C 32
#define IN_F 68

__device__ __forceinline__ float angf(float ax, float ay, float az,
                                      float bx, float by, float bz) {
    float cx = ay * bz - az * by;
    float cy = az * bx - ax * bz;
    float cz = ax * by - ay * bx;
    float cn = sqrtf(cx * cx + cy * cy + cz * cz);
    float dt = ax * bx + ay * by + az * bz;
    return atan2f(cn, dt);
}

__device__ __forceinline__ int branch_of(int m) {
    if (m == 0 || m == 10) return 0;
    if (m == 1 || m == 9)  return 1;
    if (m >= 2 && m <= 5)  return 2;
    return 3;
}

// slot(dst): group-major, then rank-in-group, then idx = dst/11
__device__ __forceinline__ int slot_of(int dst, int NB) {
    int idx = dst / 11;
    int m = dst - idx * 11;
    int g, rank;
    if (m == 0)       { g = 0; rank = 0; }
    else if (m == 10) { g = 0; rank = 1; }
    else if (m == 1)  { g = 1; rank = 0; }
    else if (m == 9)  { g = 1; rank = 1; }
    else if (m <= 5)  { g = 2; rank = m - 2; }
    else              { g = 3; rank = m - 6; }
    static const int base_nb[4] = {0, 2, 4, 8};
    return (base_nb[g] + rank) * NB + idx;
}

// --- CSR build ---------------------------------------------------------------
__global__ void k_count(const int* __restrict__ edst, int E, int* counts, int NB) {
    int t = blockIdx.x * blockDim.x + threadIdx.x;
    if (t >= E) return;
    atomicAdd(&counts[slot_of(edst[t], NB)], 1);
}

// exclusive scan of counts -> cursor, block totals -> blk
__global__ __launch_bounds__(1024) void k_scan1(const int* __restrict__ counts,
                                                int NN, int* cursor, int* blk) {
    __shared__ int wsum[16];
    int t = blockIdx.x * 1024 + threadIdx.x;
    int lane = threadIdx.x & 63;
    int wid = threadIdx.x >> 6;
    int c = (t < NN) ? counts[t] : 0;
    int inc = c;
    #pragma unroll
    for (int d = 1; d < 64; d <<= 1) {
        int v = __shfl_up(inc, d, 64);
        if (lane >= d) inc += v;
    }
    if (lane == 63) wsum[wid] = inc;
    __syncthreads();
    if (threadIdx.x < 16) {
        int v = wsum[threadIdx.x];
        int wi = v;
        #pragma unroll
        for (int d = 1; d < 16; d <<= 1) {
            int u = __shfl_up(wi, d, 64);
            if (threadIdx.x >= d) wi += u;
        }
        wsum[threadIdx.x] = wi - v;
        if (threadIdx.x == 15) blk[blockIdx.x] = wi;
    }
    __syncthreads();
    if (t < NN) cursor[t] = inc - c + wsum[wid];
}

__global__ __launch_bounds__(256) void k_scan2(int* blk, int nblk) {
    __shared__ int wsum[4];
    int lane = threadIdx.x & 63;
    int wid = threadIdx.x >> 6;
    int v = (threadIdx.x < nblk) ? blk[threadIdx.x] : 0;
    int inc = v;
    #pragma unroll
    for (int d = 1; d < 64; d <<= 1) {
        int u = __shfl_up(inc, d, 64);
        if (lane >= d) inc += u;
    }
    if (lane == 63) wsum[wid] = inc;
    __syncthreads();
    if (threadIdx.x < 4) {
        int w = wsum[threadIdx.x];
        int wi = w;
        #pragma unroll
        for (int d = 1; d < 4; d <<= 1) {
            int u = __shfl_up(wi, d, 64);
            if (threadIdx.x >= d) wi += u;
        }
        wsum[threadIdx.x] = wi - w;
    }
    __syncthreads();
    if (threadIdx.x < nblk) blk[threadIdx.x] = inc - v + wsum[wid];
}

__global__ __launch_bounds__(1024) void k_scan3(int* cursor, const int* blk, int NN) {
    int t = blockIdx.x * 1024 + threadIdx.x;
    if (t >= NN) return;
    cursor[t] += blk[blockIdx.x];
}

__global__ void k_fill(const int* __restrict__ esrc, const int* __restrict__ edst,
                       int E, int* cursor, int* __restrict__ pool_src,
                       int* __restrict__ pool_dst, int NB) {
    int t = blockIdx.x * blockDim.x + threadIdx.x;
    if (t >= E) return;
    int dst = edst[t];
    int pos = atomicAdd(&cursor[slot_of(dst, NB)], 1);
    pool_src[pos] = esrc[t];
    pool_dst[pos] = dst;
}

// --- main kernel: 1 lane = 1 edge, segmented reduction -----------------------
__global__ __launch_bounds__(256) void k_edges(
    const float* __restrict__ x_dna, const float* __restrict__ v_dna,
    const float* __restrict__ x_prot, const float* __restrict__ v_prot,
    const float* __restrict__ prot_vec, const float* __restrict__ dna_vec,
    const float* __restrict__ W1, const float* __restrict__ b1,
    const float* __restrict__ W2, const float* __restrict__ b2,
    const int* __restrict__ pool_src, const int* __restrict__ pool_dst,
    int E, float* __restrict__ conv)
{
    int t = blockIdx.x * 256 + threadIdx.x;
    int lane = threadIdx.x & 63;
    bool valid = (t < E);
    int src = 0, dst = -1;
    if (valid) { src = pool_src[t]; dst = pool_dst[t]; }
    int b = valid ? branch_of(dst % 11) : -1;

    float msg[IN_C];
    #pragma unroll
    for (int c = 0; c < IN_C; ++c) msg[c] = 0.0f;

    // process lanes in wave-uniform branch passes (1 pass for ~99.97% of waves)
    unsigned long long todo = __ballot(valid);
    while (todo) {
        int leader = __ffsll((long long)todo) - 1;
        int bb = __builtin_amdgcn_readlane(b, leader);   // uniform branch id
        bool mine = valid && (b == bb);
        if (mine) {
            const float* Wa  = W1 + bb * (IN_F * IN_C);
            const float* Wb  = W2 + bb * (IN_C * IN_C);
            const float* ba  = b1 + bb * IN_C;
            const float* bb2 = b2 + bb * IN_C;

            float vdx = v_dna[dst * 3 + 0], vdy = v_dna[dst * 3 + 1], vdz = v_dna[dst * 3 + 2];
            float nix = dna_vec[dst * 3 + 0], niy = dna_vec[dst * 3 + 1], niz = dna_vec[dst * 3 + 2];
            float vpx = v_prot[src * 3 + 0], vpy = v_prot[src * 3 + 1], vpz = v_prot[src * 3 + 2];
            float njx = prot_vec[src * 3 + 0], njy = prot_vec[src * 3 + 1], njz = prot_vec[src * 3 + 2];
            float dx = vpx - vdx, dy = vpy - vdy, dz = vpz - vdz;
            float pf[4];
            pf[0] = sqrtf(dx * dx + dy * dy + dz * dz);
            pf[1] = angf(nix, niy, niz, dx, dy, dz);
            pf[2] = angf(njx, njy, njz, dx, dy, dz);
            pf[3] = angf(nix, niy, niz, njx, njy, njz);

            float h1[IN_C];
            #pragma unroll
            for (int c = 0; c < IN_C; ++c) h1[c] = ba[c];

            const float4* xp = reinterpret_cast<const float4*>(x_prot + (size_t)src * IN_C);
            #pragma unroll
            for (int kk = 0; kk < 8; ++kk) {
                float4 xv = xp[kk];
                float fs[4] = {xv.x, xv.y, xv.z, xv.w};
                #pragma unroll
                for (int j = 0; j < 4; ++j)
                    #pragma unroll
                    for (int c = 0; c < IN_C; ++c)
                        h1[c] = fmaf(fs[j], Wa[(kk * 4 + j) * IN_C + c], h1[c]);
            }
            #pragma unroll
            for (int j = 0; j < 4; ++j)
                #pragma unroll
                for (int c = 0; c < IN_C; ++c)
                    h1[c] = fmaf(pf[j], Wa[(32 + j) * IN_C + c], h1[c]);
            const float4* xd = reinterpret_cast<const float4*>(x_dna + (size_t)dst * IN_C);
            #pragma unroll
            for (int kk = 0; kk < 8; ++kk) {
                float4 xv = xd[kk];
                float fs[4] = {xv.x, xv.y, xv.z, xv.w};
                #pragma unroll
                for (int j = 0; j < 4; ++j)
                    #pragma unroll
                    for (int c = 0; c < IN_C; ++c)
                        h1[c] = fmaf(fs[j], Wa[(36 + kk * 4 + j) * IN_C + c], h1[c]);
            }

            // layer 2 accumulates directly into msg
            #pragma unroll
            for (int c = 0; c < IN_C; ++c) msg[c] = bb2[c];
            #pragma unroll
            for (int k = 0; k < IN_C; ++k) {
                float f = fmaxf(h1[k], 0.0f);
                #pragma unroll
                for (int c = 0; c < IN_C; ++c)
                    msg[c] = fmaf(f, Wb[k * IN_C + c], msg[c]);
            }
            #pragma unroll
            for (int c = 0; c < IN_C; ++c) msg[c] = fmaxf(msg[c], 0.0f);
        }
        todo &= ~__ballot(mine);
    }

    // segmented inclusive scan over same-dst runs
    int dprev = __shfl_up(dst, 1, 64);
    bool head = (lane == 0) || (dst != dprev);
    unsigned long long H = __ballot(head);
    unsigned long long mask_le = (~0ull) >> (63 - lane);
    int segstart = 63 - __clzll(H & mask_le);
    bool cond[6];
    #pragma unroll
    for (int i = 0; i < 6; ++i) cond[i] = (lane - (1 << i)) >= segstart;

    #pragma unroll
    for (int c = 0; c < IN_C; ++c) {
        float v = msg[c];
        #pragma unroll
        for (int i = 0; i < 6; ++i) {
            float u = __shfl_up(v, 1 << i, 64);
            v += cond[i] ? u : 0.0f;
        }
        msg[c] = v;
    }

    bool is_end = (lane == 63) || (((H >> 1) >> lane) & 1ull);
    if (is_end && dst >= 0) {
        float* cv = conv + (size_t)dst * IN_C;
        #pragma unroll
        for (int c = 0; c < IN_C; ++c)
            atomicAdd(&cv[c], msg[c]);
    }
}

// --- fallback (ws too small): per-edge atomics -------------------------------
__global__ __launch_bounds__(256) void k_edges_fallback(
    const float* __restrict__ x_dna, const float* __restrict__ v_dna,
    const float* __restrict__ x_prot, const float* __restrict__ v_prot,
    const float* __restrict__ prot_vec, const float* __restrict__ dna_vec,
    const int* __restrict__ esrc, const int* __restrict__ edst,
    const float* __restrict__ W1, const float* __restrict__ b1,
    const float* __restrict__ W2, const float* __restrict__ b2,
    int E, float* __restrict__ conv)
{
    int t = blockIdx.x * blockDim.x + threadIdx.x;
    if (t >= E) return;
    int src = esrc[t], dst = edst[t];
    int b = branch_of(dst % 11);
    const float* Wa  = W1 + b * (IN_F * IN_C);
    const float* Wb  = W2 + b * (IN_C * IN_C);
    const float* ba  = b1 + b * IN_C;
    const float* bb2 = b2 + b * IN_C;

    float vdx = v_dna[dst * 3 + 0], vdy = v_dna[dst * 3 + 1], vdz = v_dna[dst * 3 + 2];
    float vpx = v_prot[src * 3 + 0], vpy = v_prot[src * 3 + 1], vpz = v_prot[src * 3 + 2];
    float nix = dna_vec[dst * 3 + 0], niy = dna_vec[dst * 3 + 1], niz = dna_vec[dst * 3 + 2];
    float njx = prot_vec[src * 3 + 0], njy = prot_vec[src * 3 + 1], njz = prot_vec[src * 3 + 2];
    float dx = vpx - vdx, dy = vpy - vdy, dz = vpz - vdz;
    float pf[4];
    pf[0] = sqrtf(dx * dx + dy * dy + dz * dz);
    pf[1] = angf(nix, niy, niz, dx, dy, dz);
    pf[2] = angf(njx, njy, njz, dx, dy, dz);
    pf[3] = angf(nix, niy, niz, njx, njy, njz);

    float h1[IN_C];
    #pragma unroll
    for (int c = 0; c < IN_C; ++c) h1[c] = ba[c];
    const float4* xp = reinterpret_cast<const float4*>(x_prot + (size_t)src * IN_C);
    #pragma unroll
    for (int kk = 0; kk < 8; ++kk) {
        float4 xv = xp[kk];
        float fs[4] = {xv.x, xv.y, xv.z, xv.w};
        #pragma unroll
        for (int j = 0; j < 4; ++j)
            #pragma unroll
            for (int c = 0; c < IN_C; ++c)
                h1[c] = fmaf(fs[j], Wa[(kk * 4 + j) * IN_C + c], h1[c]);
    }
    #pragma unroll
    for (int j = 0; j < 4; ++j)
        #pragma unroll
        for (int c = 0; c < IN_C; ++c)
            h1[c] = fmaf(pf[j], Wa[(32 + j) * IN_C + c], h1[c]);
    const float4* xd = reinterpret_cast<const float4*>(x_dna + (size_t)dst * IN_C);
    #pragma unroll
    for (int kk = 0; kk < 8; ++kk) {
        float4 xv = xd[kk];
        float fs[4] = {xv.x, xv.y, xv.z, xv.w};
        #pragma unroll
        for (int j = 0; j < 4; ++j)
            #pragma unroll
            for (int c = 0; c < IN_C; ++c)
                h1[c] = fmaf(fs[j], Wa[(36 + kk * 4 + j) * IN_C + c], h1[c]);
    }
    float h2[IN_C];
    #pragma unroll
    for (int c = 0; c < IN_C; ++c) h2[c] = bb2[c];
    #pragma unroll
    for (int k = 0; k < IN_C; ++k) {
        float f = fmaxf(h1[k], 0.0f);
        #pragma unroll
        for (int c = 0; c < IN_C; ++c)
            h2[c] = fmaf(f, Wb[k * IN_C + c], h2[c]);
    }
    float* cv = conv + (size_t)dst * IN_C;
    #pragma unroll
    for (int c = 0; c < IN_C; ++c)
        atomicAdd(&cv[c], fmaxf(h2[c], 0.0f));
}

extern "C" void kernel_launch(void* const* d_in, const int* in_sizes, int n_in,
                              void* d_out, int out_size, void* d_ws, size_t ws_size,
                              hipStream_t stream) {
    const float* x_dna    = (const float*)d_in[0];
    const float* v_dna    = (const float*)d_in[1];
    const float* x_prot   = (const float*)d_in[2];
    const float* v_prot   = (const float*)d_in[3];
    const float* prot_vec = (const float*)d_in[4];
    const float* dna_vec  = (const float*)d_in[5];
    const int*   esrc     = (const int*)d_in[6];
    const int*   edst     = (const int*)d_in[7];
    const float* W1       = (const float*)d_in[8];
    const float* b1       = (const float*)d_in[9];
    const float* W2       = (const float*)d_in[10];
    const float* b2       = (const float*)d_in[11];

    const int E  = in_sizes[6];
    const int ND = in_sizes[0] / IN_C;       // N_DNA
    const int NB = ND / 11;
    const int NN = NB * 11;
    const int half = out_size / 2;
    float* out  = (float*)d_out;
    float* conv = out + half;

    const int nblk_scan = (NN + 1023) / 1024;
    const size_t ws_need = ((size_t)2 * NN + 256 + E) * sizeof(int);
    const int eb = (E + 255) / 256;

    if (ws_size >= ws_need && nblk_scan <= 256 && (size_t)half >= (size_t)E) {
        int* counts   = (int*)d_ws;
        int* cursor   = counts + NN;
        int* blk      = cursor + NN;         // 256 ints
        int* pool_src = blk + 256;           // E ints
        int* pool_dst = (int*)out;           // scratch in out[0:half], E ints

        hipMemsetAsync(counts, 0, (size_t)NN * sizeof(int), stream);
        k_count<<<eb, 256, 0, stream>>>(edst, E, counts, NB);
        k_scan1<<<nblk_scan, 1024, 0, stream>>>(counts, NN, cursor, blk);
        k_scan2<<<1, 256, 0, stream>>>(blk, nblk_scan);
        k_scan3<<<nblk_scan, 1024, 0, stream>>>(cursor, blk, NN);
        k_fill<<<eb, 256, 0, stream>>>(esrc, edst, E, cursor, pool_src, pool_dst, NB);

        hipMemsetAsync(conv, 0, (size_t)half * sizeof(float), stream);
        k_edges<<<eb, 256, 0, stream>>>(
            x_dna, v_dna, x_prot, v_prot, prot_vec, dna_vec,
            W1, b1, W2, b2, pool_src, pool_dst, E, conv);
    } else {
        hipMemsetAsync(conv, 0, (size_t)half * sizeof(float), stream);
        k_edges_fallback<<<eb, 256, 0, stream>>>(
            x_dna, v_dna, x_prot, v_prot, prot_vec, dna_vec,
            esrc, edst, W1, b1, W2, b2, E, conv);
    }

    // out == conv (messages >= 0 -> relu(agg) == agg)
    hipMemcpyAsync(out, conv, (size_t)half * sizeof(float),
                   hipMemcpyDeviceToDevice, stream);
}